// Round 1
// baseline (37.437 us; speedup 1.0000x reference)
//
#include <hip/hip_runtime.h>

#define NU 8192
#define NI 8192
#define DM 32
#define KC 32
#define HEADS 4
#define HK 8
#define BIASV 0.1f

// ---------------- K1: keys = U@Wk+bk (raw); q = rowsoftmax_perhead(I@Wq+bq) ----
// grid: 64 blocks x 256 threads. blocks 0..31 -> users/keys, 32..63 -> items/queries.
__global__ __launch_bounds__(256) void k_embed(
    const float* __restrict__ U, const float* __restrict__ I,
    const float* __restrict__ Wk, const float* __restrict__ bk,
    const float* __restrict__ Wq, const float* __restrict__ bq,
    float* __restrict__ keys, float* __restrict__ qout, int* __restrict__ cnt)
{
    __shared__ float Ws[DM * KC];
    __shared__ float bs[KC];
    const int half = blockIdx.x >> 5;   // 0 users, 1 items
    const int blk  = blockIdx.x & 31;
    const float* W = half ? Wq : Wk;
    const float* b = half ? bq : bk;
    const float* E = half ? I  : U;

    for (int t = threadIdx.x; t < DM * KC; t += 256) Ws[t] = W[t];
    if (threadIdx.x < KC) bs[threadIdx.x] = b[threadIdx.x];
    if (blockIdx.x == 0 && threadIdx.x == 0) *cnt = 0;
    __syncthreads();

    const int row = blk * 256 + threadIdx.x;
    float e[DM];
    const float4* ev = (const float4*)(E + row * DM);
    #pragma unroll
    for (int j = 0; j < DM / 4; ++j) {
        float4 v = ev[j];
        e[4*j+0] = v.x; e[4*j+1] = v.y; e[4*j+2] = v.z; e[4*j+3] = v.w;
    }
    float o[KC];
    #pragma unroll
    for (int c = 0; c < KC; ++c) {
        float s = bs[c];
        #pragma unroll
        for (int dd = 0; dd < DM; ++dd) s += e[dd] * Ws[dd * KC + c];
        o[c] = s;
    }

    if (half == 0) {
        float4* dst = (float4*)(keys + row * KC);
        #pragma unroll
        for (int j = 0; j < KC / 4; ++j)
            dst[j] = make_float4(o[4*j], o[4*j+1], o[4*j+2], o[4*j+3]);
    } else {
        // per-head softmax over the 8 channels of each head
        #pragma unroll
        for (int h = 0; h < HEADS; ++h) {
            float m = o[h*HK];
            #pragma unroll
            for (int c = 1; c < HK; ++c) m = fmaxf(m, o[h*HK + c]);
            float sum = 0.f;
            #pragma unroll
            for (int c = 0; c < HK; ++c) { float t = __expf(o[h*HK + c] - m); o[h*HK + c] = t; sum += t; }
            float inv = 1.f / sum;
            #pragma unroll
            for (int c = 0; c < HK; ++c) o[h*HK + c] *= inv;
        }
        float4* dst = (float4*)(qout + row * KC);
        #pragma unroll
        for (int j = 0; j < KC / 4; ++j)
            dst[j] = make_float4(o[4*j], o[4*j+1], o[4*j+2], o[4*j+3]);
    }
}

// ---------------- K2: per-column max & sum(exp) over 8192 users ---------------
// grid: 32 blocks (one per column) x 256 threads
__global__ __launch_bounds__(256) void k_colred(
    const float* __restrict__ keys, float* __restrict__ cm, float* __restrict__ cs)
{
    const int c = blockIdx.x;
    __shared__ float red[256];
    float m = -1e30f;
    for (int u = threadIdx.x; u < NU; u += 256) m = fmaxf(m, keys[u * KC + c]);
    red[threadIdx.x] = m; __syncthreads();
    for (int s = 128; s > 0; s >>= 1) {
        if (threadIdx.x < s) red[threadIdx.x] = fmaxf(red[threadIdx.x], red[threadIdx.x + s]);
        __syncthreads();
    }
    m = red[0]; __syncthreads();
    float sum = 0.f;
    for (int u = threadIdx.x; u < NU; u += 256) sum += __expf(keys[u * KC + c] - m);
    red[threadIdx.x] = sum; __syncthreads();
    for (int s = 128; s > 0; s >>= 1) {
        if (threadIdx.x < s) red[threadIdx.x] += red[threadIdx.x + s];
        __syncthreads();
    }
    if (threadIdx.x == 0) { cm[c] = m; cs[c] = red[0]; }
}

// ---------------- K3: column softmax in place + active-(u,h) compaction -------
// bound: sum_c k*q <= max_c k  (q>=0, sum_c q = 1) -> pair inactive if max<=BIAS
// grid: 32 blocks x 256 threads (one thread per user)
__global__ __launch_bounds__(256) void k_soft_act(
    float* __restrict__ keys, const float* __restrict__ cm, const float* __restrict__ cs,
    int* __restrict__ cnt, int* __restrict__ act)
{
    __shared__ float cms[KC], csi[KC];
    if (threadIdx.x < KC) cms[threadIdx.x] = cm[threadIdx.x];
    else if (threadIdx.x < 2 * KC) csi[threadIdx.x - KC] = 1.f / cs[threadIdx.x - KC];
    __syncthreads();

    const int u = blockIdx.x * 256 + threadIdx.x;
    float k[KC];
    float4* rv = (float4*)(keys + u * KC);
    #pragma unroll
    for (int j = 0; j < KC / 4; ++j) {
        float4 v = rv[j];
        k[4*j+0] = v.x; k[4*j+1] = v.y; k[4*j+2] = v.z; k[4*j+3] = v.w;
    }
    #pragma unroll
    for (int c = 0; c < KC; ++c) k[c] = __expf(k[c] - cms[c]) * csi[c];
    #pragma unroll
    for (int j = 0; j < KC / 4; ++j)
        rv[j] = make_float4(k[4*j], k[4*j+1], k[4*j+2], k[4*j+3]);

    #pragma unroll
    for (int h = 0; h < HEADS; ++h) {
        float m = k[h*HK];
        #pragma unroll
        for (int c = 1; c < HK; ++c) m = fmaxf(m, k[h*HK + c]);
        if (m > BIASV) {
            int p = atomicAdd(cnt, 1);
            act[p] = (u << 2) | h;
        }
    }
}

// ---------------- K4: att accumulation over active pairs + reproj + residual --
// grid: 1024 blocks x 256 threads; each block does 8 items (32 threads/item)
__global__ __launch_bounds__(256) void k_final(
    const float* __restrict__ I, const float* __restrict__ U,
    const float* __restrict__ keys, const float* __restrict__ q,
    const float* __restrict__ Wr, const float* __restrict__ br,
    const int* __restrict__ cnt, const int* __restrict__ act,
    float* __restrict__ out)
{
    __shared__ float q_s[8][KC];
    __shared__ float agg[8][HEADS * DM];
    const int il = threadIdx.x >> 5;       // item within block: 0..7
    const int dd = threadIdx.x & 31;       // d-channel: 0..31
    const int item = blockIdx.x * 8 + il;

    q_s[il][dd] = q[item * KC + dd];
    __syncthreads();

    const int n = *cnt;
    float a0 = 0.f, a1 = 0.f, a2 = 0.f, a3 = 0.f;
    for (int p = 0; p < n; ++p) {
        const int pr = act[p];
        const int u = pr >> 2;
        const int h = pr & 3;
        const float* kr = keys + u * KC + h * HK;
        const float* qr = &q_s[il][h * HK];
        float s = 0.f;
        #pragma unroll
        for (int c = 0; c < HK; ++c) s += kr[c] * qr[c];
        s -= BIASV;
        if (s > 0.f) {
            float add = s * U[u * DM + dd];
            a0 += (h == 0) ? add : 0.f;
            a1 += (h == 1) ? add : 0.f;
            a2 += (h == 2) ? add : 0.f;
            a3 += (h == 3) ? add : 0.f;
        }
    }
    agg[il][0  + dd] = a0;
    agg[il][32 + dd] = a1;
    agg[il][64 + dd] = a2;
    agg[il][96 + dd] = a3;
    __syncthreads();

    const int c = dd;
    float acc = br[c];
    #pragma unroll 8
    for (int j = 0; j < HEADS * DM; ++j) acc += agg[il][j] * Wr[j * KC + c];
    out[item * KC + c] = I[item * KC + c] + acc;
}

extern "C" void kernel_launch(void* const* d_in, const int* in_sizes, int n_in,
                              void* d_out, int out_size, void* d_ws, size_t ws_size,
                              hipStream_t stream) {
    const float* U  = (const float*)d_in[0];
    const float* I  = (const float*)d_in[1];
    const float* Wk = (const float*)d_in[2];
    const float* bk = (const float*)d_in[3];
    const float* Wq = (const float*)d_in[4];
    const float* bq = (const float*)d_in[5];
    const float* Wr = (const float*)d_in[6];
    const float* br = (const float*)d_in[7];
    float* out = (float*)d_out;

    float* ws_keys = (float*)d_ws;               // NU*KC
    float* ws_q    = ws_keys + NU * KC;          // NI*KC
    float* ws_cm   = ws_q + NI * KC;             // KC
    float* ws_cs   = ws_cm + KC;                 // KC
    int*   ws_cnt  = (int*)(ws_cs + KC);         // 1 (+pad)
    int*   ws_act  = ws_cnt + 4;                 // NU*HEADS

    k_embed<<<64, 256, 0, stream>>>(U, I, Wk, bk, Wq, bq, ws_keys, ws_q, ws_cnt);
    k_colred<<<32, 256, 0, stream>>>(ws_keys, ws_cm, ws_cs);
    k_soft_act<<<32, 256, 0, stream>>>(ws_keys, ws_cm, ws_cs, ws_cnt, ws_act);
    k_final<<<NI / 8, 256, 0, stream>>>(I, U, ws_keys, ws_q, Wr, br, ws_cnt, ws_act, out);
}

// Round 2
// 17.990 us; speedup vs baseline: 2.0810x; 2.0810x over previous
//
#include <hip/hip_runtime.h>

#define NU 8192
#define NI 8192
#define DM 32
#define KC 32
#define HEADS 4
#define HK 8
#define BIASV 0.1f

#define K1_T 64
#define UBLK (NU / K1_T)        // 128 user blocks in K1
#define K2_BLOCKS 64
#define K2_T 128                // users per block in K2
#define SEG_CAP (K2_T * HEADS)  // 512 max active pairs per segment

// ---- K1: rows 0..8191 = users -> raw keys + per-block col partial sum(exp);
//          rows 8192..16383 = items -> q row-softmax. 256 blocks x 64 threads.
__global__ __launch_bounds__(64) void k_embed(
    const float* __restrict__ U, const float* __restrict__ I,
    const float* __restrict__ Wk, const float* __restrict__ bk,
    const float* __restrict__ Wq, const float* __restrict__ bq,
    float* __restrict__ keys, float* __restrict__ qout, float* __restrict__ part)
{
    __shared__ float Ws[DM * KC];
    __shared__ float bs[KC];
    const int half = blockIdx.x >> 7;   // 0 users, 1 items
    const int blk  = blockIdx.x & 127;
    const float* W = half ? Wq : Wk;
    const float* b = half ? bq : bk;
    const float* E = half ? I  : U;

    #pragma unroll
    for (int t = 0; t < DM * KC / K1_T; ++t) Ws[t * K1_T + threadIdx.x] = W[t * K1_T + threadIdx.x];
    if (threadIdx.x < KC) bs[threadIdx.x] = b[threadIdx.x];
    __syncthreads();

    const int row = blk * K1_T + threadIdx.x;
    float e[DM];
    const float4* ev = (const float4*)(E + row * DM);
    #pragma unroll
    for (int j = 0; j < DM / 4; ++j) {
        float4 v = ev[j];
        e[4*j+0] = v.x; e[4*j+1] = v.y; e[4*j+2] = v.z; e[4*j+3] = v.w;
    }
    float o[KC];
    #pragma unroll
    for (int c = 0; c < KC; ++c) {
        float s = bs[c];
        #pragma unroll
        for (int dd = 0; dd < DM; ++dd) s += e[dd] * Ws[dd * KC + c];
        o[c] = s;
    }

    if (half == 0) {
        float4* dst = (float4*)(keys + row * KC);
        #pragma unroll
        for (int j = 0; j < KC / 4; ++j)
            dst[j] = make_float4(o[4*j], o[4*j+1], o[4*j+2], o[4*j+3]);
        // per-block partial column sums of exp(key). |key| ~< 4 so no max shift needed in fp32.
        float s[KC];
        #pragma unroll
        for (int c = 0; c < KC; ++c) s[c] = __expf(o[c]);
        #pragma unroll
        for (int m = 1; m < 64; m <<= 1) {
            #pragma unroll
            for (int c = 0; c < KC; ++c) s[c] += __shfl_xor(s[c], m, 64);
        }
        if (threadIdx.x == 0) {
            float4* pd = (float4*)(part + blk * KC);
            #pragma unroll
            for (int j = 0; j < KC / 4; ++j)
                pd[j] = make_float4(s[4*j], s[4*j+1], s[4*j+2], s[4*j+3]);
        }
    } else {
        #pragma unroll
        for (int h = 0; h < HEADS; ++h) {
            float m = o[h*HK];
            #pragma unroll
            for (int c = 1; c < HK; ++c) m = fmaxf(m, o[h*HK + c]);
            float sum = 0.f;
            #pragma unroll
            for (int c = 0; c < HK; ++c) { float t = __expf(o[h*HK + c] - m); o[h*HK + c] = t; sum += t; }
            float inv = 1.f / sum;
            #pragma unroll
            for (int c = 0; c < HK; ++c) o[h*HK + c] *= inv;
        }
        float4* dst = (float4*)(qout + (row - NU) * KC);
        #pragma unroll
        for (int j = 0; j < KC / 4; ++j)
            dst[j] = make_float4(o[4*j], o[4*j+1], o[4*j+2], o[4*j+3]);
    }
}

// ---- K2: merge partials (redundant per block), normalize keys in place,
//          per-(u,h) activity test -> per-block compacted segment list.
//          bound: sum_c k*q <= max_c k (q>=0, sum_c q=1) -> inactive if max<=BIAS
__global__ __launch_bounds__(K2_T) void k_norm_act(
    float* __restrict__ keys, const float* __restrict__ part,
    int* __restrict__ cnt, int* __restrict__ act)
{
    __shared__ float sinv[KC];
    __shared__ int lcnt;
    __shared__ int list[SEG_CAP];
    if (threadIdx.x == 0) lcnt = 0;
    if (threadIdx.x < KC) {
        float s = 0.f;
        for (int b = 0; b < UBLK; ++b) s += part[b * KC + threadIdx.x];
        sinv[threadIdx.x] = 1.f / s;
    }
    __syncthreads();

    const int u = blockIdx.x * K2_T + threadIdx.x;
    float k[KC];
    float4* rv = (float4*)(keys + u * KC);
    #pragma unroll
    for (int j = 0; j < KC / 4; ++j) {
        float4 v = rv[j];
        k[4*j+0] = v.x; k[4*j+1] = v.y; k[4*j+2] = v.z; k[4*j+3] = v.w;
    }
    #pragma unroll
    for (int c = 0; c < KC; ++c) k[c] = __expf(k[c]) * sinv[c];
    #pragma unroll
    for (int j = 0; j < KC / 4; ++j)
        rv[j] = make_float4(k[4*j], k[4*j+1], k[4*j+2], k[4*j+3]);

    #pragma unroll
    for (int h = 0; h < HEADS; ++h) {
        float m = k[h*HK];
        #pragma unroll
        for (int c = 1; c < HK; ++c) m = fmaxf(m, k[h*HK + c]);
        if (m > BIASV) {
            int p = atomicAdd(&lcnt, 1);
            list[p] = (u << 2) | h;
        }
    }
    __syncthreads();
    for (int t = threadIdx.x; t < lcnt; t += K2_T)
        act[blockIdx.x * SEG_CAP + t] = list[t];
    if (threadIdx.x == 0) cnt[blockIdx.x] = lcnt;
}

// ---- K3: epilogue. total==0 fast path: out = I + br (pure streaming).
//          general path: accumulate active pairs, reproj, residual.
__global__ __launch_bounds__(256) void k_final(
    const float* __restrict__ I, const float* __restrict__ U,
    const float* __restrict__ keys, const float* __restrict__ q,
    const float* __restrict__ Wr, const float* __restrict__ br,
    const int* __restrict__ cnt, const int* __restrict__ act,
    float* __restrict__ out)
{
    __shared__ int cnts[K2_BLOCKS];
    __shared__ int total_s;
    const int il = threadIdx.x >> 5;       // item within block: 0..7
    const int dd = threadIdx.x & 31;       // channel: 0..31
    const int item = blockIdx.x * 8 + il;

    if (threadIdx.x < K2_BLOCKS) cnts[threadIdx.x] = cnt[threadIdx.x];
    __syncthreads();
    if (threadIdx.x == 0) {
        int t = 0;
        for (int b = 0; b < K2_BLOCKS; ++b) t += cnts[b];
        total_s = t;
    }
    __syncthreads();

    const float resid = I[item * KC + dd];
    const float bias  = br[dd];
    if (total_s == 0) {                    // block-uniform -> safe early return
        out[item * KC + dd] = resid + bias;
        return;
    }

    __shared__ float q_s[8][KC];
    __shared__ float agg[8][HEADS * DM];
    q_s[il][dd] = q[item * KC + dd];
    __syncthreads();

    float a0 = 0.f, a1 = 0.f, a2 = 0.f, a3 = 0.f;
    for (int b = 0; b < K2_BLOCKS; ++b) {
        const int n = cnts[b];
        const int* __restrict__ seg = act + b * SEG_CAP;
        for (int p = 0; p < n; ++p) {
            const int pr = seg[p];
            const int u = pr >> 2;
            const int h = pr & 3;
            const float* kr = keys + u * KC + h * HK;
            const float* qr = &q_s[il][h * HK];
            float s = 0.f;
            #pragma unroll
            for (int c = 0; c < HK; ++c) s += kr[c] * qr[c];
            s -= BIASV;
            if (s > 0.f) {
                float add = s * U[u * DM + dd];
                a0 += (h == 0) ? add : 0.f;
                a1 += (h == 1) ? add : 0.f;
                a2 += (h == 2) ? add : 0.f;
                a3 += (h == 3) ? add : 0.f;
            }
        }
    }
    agg[il][0  + dd] = a0;
    agg[il][32 + dd] = a1;
    agg[il][64 + dd] = a2;
    agg[il][96 + dd] = a3;
    __syncthreads();

    float acc = bias;
    #pragma unroll 8
    for (int j = 0; j < HEADS * DM; ++j) acc += agg[il][j] * Wr[j * KC + dd];
    out[item * KC + dd] = resid + acc;
}

extern "C" void kernel_launch(void* const* d_in, const int* in_sizes, int n_in,
                              void* d_out, int out_size, void* d_ws, size_t ws_size,
                              hipStream_t stream) {
    const float* U  = (const float*)d_in[0];
    const float* I  = (const float*)d_in[1];
    const float* Wk = (const float*)d_in[2];
    const float* bk = (const float*)d_in[3];
    const float* Wq = (const float*)d_in[4];
    const float* bq = (const float*)d_in[5];
    const float* Wr = (const float*)d_in[6];
    const float* br = (const float*)d_in[7];
    float* out = (float*)d_out;

    float* ws_keys = (float*)d_ws;                 // NU*KC
    float* ws_q    = ws_keys + NU * KC;            // NI*KC
    float* ws_part = ws_q + NI * KC;               // UBLK*KC
    int*   ws_cnt  = (int*)(ws_part + UBLK * KC);  // K2_BLOCKS
    int*   ws_act  = ws_cnt + K2_BLOCKS;           // K2_BLOCKS*SEG_CAP

    k_embed<<<256, K1_T, 0, stream>>>(U, I, Wk, bk, Wq, bq, ws_keys, ws_q, ws_part);
    k_norm_act<<<K2_BLOCKS, K2_T, 0, stream>>>(ws_keys, ws_part, ws_cnt, ws_act);
    k_final<<<NI / 8, 256, 0, stream>>>(I, U, ws_keys, ws_q, Wr, br, ws_cnt, ws_act, out);
}